// Round 4
// baseline (493.727 us; speedup 1.0000x reference)
//
#include <hip/hip_runtime.h>
#include <stdint.h>

// PCLayer closed form: out = (t - b) @ W',  W'^T = M @ W^T,
// M = 0.01*I + lr*(-45E + 120E^2),  E = lr*W^T W   (E^3 term < 1e-5, dropped;
// empirically verified identical absmax in rounds 2/3).
// LDS-FREE GEMM: wave owns 32 rows (A read once, fp32->bf16 in-reg, 2-ahead
// register prefetch); B fragments read direct from L1/L2-hot global (B <= 4.7MB).
// No barriers, no LDS, no staging passes. 8 launches, no memset, no atomics.

typedef short bf16x8 __attribute__((ext_vector_type(8)));   // 8 bf16 = 4 VGPRs
typedef float f32x4  __attribute__((ext_vector_type(4)));
typedef unsigned short u16;

__device__ __forceinline__ u16 f2bf(float f) {  // round-to-nearest-even
  union { float f; unsigned int i; } x; x.f = f;
  unsigned int r = x.i + 0x7fffu + ((x.i >> 16) & 1u);
  return (u16)(r >> 16);
}
__device__ __forceinline__ u16 f2bfu(float f) { // round-half-up (hot path, 2 ops)
  union { float f; unsigned int i; } x; x.f = f;
  return (u16)((x.i + 0x8000u) >> 16);
}
__device__ __forceinline__ bf16x8 cvt8(float4 a, float4 b, float4 ba, float4 bb) {
  bf16x8 v;
  v[0] = (short)f2bfu(a.x - ba.x); v[1] = (short)f2bfu(a.y - ba.y);
  v[2] = (short)f2bfu(a.z - ba.z); v[3] = (short)f2bfu(a.w - ba.w);
  v[4] = (short)f2bfu(b.x - bb.x); v[5] = (short)f2bfu(b.y - bb.y);
  v[6] = (short)f2bfu(b.z - bb.z); v[7] = (short)f2bfu(b.w - bb.w);
  return v;
}

// C[M,N] = alpha * A[M,K] @ B[N,K]^T, tile 128x192, grid (M/128, N/192, z).
// ABF16=0: A fp32, bias-subtract + cvt in registers. ABF16=1: A bf16 direct.
// Stores fp32 partial at Cf + blockIdx.z*zstride. kc must be a multiple of 128.
template<int ABF16>
__global__ __launch_bounds__(256, 1)
void gemm_d(const void* __restrict__ Ap, const float* __restrict__ bias,
            const u16* __restrict__ B, float* __restrict__ Cf,
            float alpha, int K, int ldc, int kc, long zstride)
{
  const int tid = threadIdx.x, w = tid >> 6, lane = tid & 63;
  const int lm = lane & 15, quad = lane >> 4;
  const int m0 = blockIdx.x * 128, n0 = blockIdx.y * 192;
  const long k0 = (long)blockIdx.z * kc;
  const long arow = (long)(m0 + w * 32 + lm) * K + k0 + quad * 8;
  const float* At  = (const float*)Ap + arow;
  const u16*   A16 = (const u16*)Ap + arow;
  const u16*   Bg  = B + (long)(n0 + lm) * K + k0 + quad * 8;
  const float* bp  = bias + k0 + quad * 8;   // used only when ABF16==0

  f32x4 acc[2][12];
#pragma unroll
  for (int i = 0; i < 2; ++i)
#pragma unroll
    for (int j = 0; j < 12; ++j) acc[i][j] = (f32x4){0.f, 0.f, 0.f, 0.f};

  // 2-step-ahead prefetch (ping-pong pp=0/1 inside a 128-wide outer step)
  float4 ap[2][2][2][2];   // [pp][i][s][h], ABF16==0
  bf16x8 aq[2][2][2];      // [pp][i][s],    ABF16==1
#pragma unroll
  for (int pp = 0; pp < 2; ++pp)
#pragma unroll
    for (int i = 0; i < 2; ++i)
#pragma unroll
      for (int s = 0; s < 2; ++s) {
        const long o = (long)i * 16 * K + pp * 64 + s * 32;
        if constexpr (ABF16 == 0) {
          ap[pp][i][s][0] = *(const float4*)(At + o);
          ap[pp][i][s][1] = *(const float4*)(At + o + 4);
        } else {
          aq[pp][i][s] = *(const bf16x8*)(A16 + o);
        }
      }

#pragma unroll 1
  for (int kk = 0; kk < kc; kk += 128) {
#pragma unroll
    for (int pp = 0; pp < 2; ++pp) {
      const int kb = kk + pp * 64;
      bf16x8 af[2][2];
      if constexpr (ABF16 == 0) {
        float4 bb[2][2];
#pragma unroll
        for (int s = 0; s < 2; ++s) {
          bb[s][0] = *(const float4*)(bp + kb + s * 32);
          bb[s][1] = *(const float4*)(bp + kb + s * 32 + 4);
        }
#pragma unroll
        for (int i = 0; i < 2; ++i)
#pragma unroll
          for (int s = 0; s < 2; ++s)
            af[i][s] = cvt8(ap[pp][i][s][0], ap[pp][i][s][1], bb[s][0], bb[s][1]);
      } else {
#pragma unroll
        for (int i = 0; i < 2; ++i)
#pragma unroll
          for (int s = 0; s < 2; ++s) af[i][s] = aq[pp][i][s];
      }
      // reload this buffer 128 columns ahead (consumed 2 pp-phases later)
      const int kn = kb + 128;
      if (kn < kc) {
#pragma unroll
        for (int i = 0; i < 2; ++i)
#pragma unroll
          for (int s = 0; s < 2; ++s) {
            const long o = (long)i * 16 * K + kn + s * 32;
            if constexpr (ABF16 == 0) {
              ap[pp][i][s][0] = *(const float4*)(At + o);
              ap[pp][i][s][1] = *(const float4*)(At + o + 4);
            } else {
              aq[pp][i][s] = *(const bf16x8*)(A16 + o);
            }
          }
      }
#pragma unroll
      for (int s = 0; s < 2; ++s)
#pragma unroll
        for (int j = 0; j < 12; ++j) {
          const bf16x8 bv = *(const bf16x8*)(Bg + (long)j * 16 * K + kb + s * 32);
          acc[0][j] = __builtin_amdgcn_mfma_f32_16x16x32_bf16(af[0][s], bv, acc[0][j], 0, 0, 0);
          acc[1][j] = __builtin_amdgcn_mfma_f32_16x16x32_bf16(af[1][s], bv, acc[1][j], 0, 0, 0);
        }
    }
  }

  // C/D layout (m89-verified): col = lane&15, row = quad*4 + reg
  const long zoff = (long)blockIdx.z * zstride;
  const int rb = m0 + w * 32 + quad * 4;
#pragma unroll
  for (int i = 0; i < 2; ++i)
#pragma unroll
    for (int j = 0; j < 12; ++j) {
      const int col = n0 + j * 16 + lm;
#pragma unroll
      for (int r = 0; r < 4; ++r)
        Cf[zoff + (long)(rb + i * 16 + r) * ldc + col] = alpha * acc[i][j][r];
    }
}

// W[3072,768] fp32 -> Wb bf16 [3072,768] + WTb bf16 [768,3072]
__global__ void conv_w(const float* __restrict__ W, u16* __restrict__ Wb,
                       u16* __restrict__ WTb)
{
  const int i4 = blockIdx.x * 256 + threadIdx.x;   // < 589824
  const float4 v = ((const float4*)W)[i4];
  ushort4 o;
  o.x = f2bf(v.x); o.y = f2bf(v.y); o.z = f2bf(v.z); o.w = f2bf(v.w);
  ((ushort4*)Wb)[i4] = o;
  const int r = i4 / 192, c = (i4 - r * 192) * 4;
  WTb[(long)(c + 0) * 3072 + r] = o.x;   // 2B scatter; 4.7MB, L2/L3-absorbed
  WTb[(long)(c + 1) * 3072 + r] = o.y;
  WTb[(long)(c + 2) * 3072 + r] = o.z;
  WTb[(long)(c + 3) * 3072 + r] = o.w;
}

// Ef = sum_{z<8} Ep[z];  Eb = bf16(Ef)
__global__ void red_e(const float* __restrict__ Ep, float* __restrict__ Ef,
                      u16* __restrict__ Eb)
{
  const int i4 = blockIdx.x * 256 + threadIdx.x;   // < 147456
  float4 s = make_float4(0.f, 0.f, 0.f, 0.f);
#pragma unroll
  for (int z = 0; z < 8; ++z) {
    const float4 p = ((const float4*)Ep)[(long)z * 147456 + i4];
    s.x += p.x; s.y += p.y; s.z += p.z; s.w += p.w;
  }
  ((float4*)Ef)[i4] = s;
  ushort4 o; o.x = f2bf(s.x); o.y = f2bf(s.y); o.z = f2bf(s.z); o.w = f2bf(s.w);
  ((ushort4*)Eb)[i4] = o;
}

// Mb = bf16(0.01*I + lr*(-45*Ef + 120*sum_{z<6} P2p[z]))
__global__ void red_m(const float* __restrict__ P2p, const float* __restrict__ Ef,
                      u16* __restrict__ Mb, float lr)
{
  const int i4 = blockIdx.x * 256 + threadIdx.x;   // < 147456
  float4 s = make_float4(0.f, 0.f, 0.f, 0.f);
#pragma unroll
  for (int z = 0; z < 6; ++z) {
    const float4 p = ((const float4*)P2p)[(long)z * 147456 + i4];
    s.x += p.x; s.y += p.y; s.z += p.z; s.w += p.w;
  }
  const float4 e = ((const float4*)Ef)[i4];
  const int r = i4 / 192, c = (i4 - r * 192) * 4;
  float4 m;
  m.x = lr * (-45.f * e.x + 120.f * s.x) + (r == c + 0 ? 0.01f : 0.f);
  m.y = lr * (-45.f * e.y + 120.f * s.y) + (r == c + 1 ? 0.01f : 0.f);
  m.z = lr * (-45.f * e.z + 120.f * s.z) + (r == c + 2 ? 0.01f : 0.f);
  m.w = lr * (-45.f * e.w + 120.f * s.w) + (r == c + 3 ? 0.01f : 0.f);
  ushort4 o; o.x = f2bf(m.x); o.y = f2bf(m.y); o.z = f2bf(m.z); o.w = f2bf(m.w);
  ((ushort4*)Mb)[i4] = o;
}

// W'Tb = bf16(sum_{z<3} Wp[z])   [768,3072]
__global__ void red_w(const float* __restrict__ Wp, u16* __restrict__ WTpb)
{
  const int i4 = blockIdx.x * 256 + threadIdx.x;   // < 589824
  float4 s = make_float4(0.f, 0.f, 0.f, 0.f);
#pragma unroll
  for (int z = 0; z < 3; ++z) {
    const float4 p = ((const float4*)Wp)[(long)z * 589824 + i4];
    s.x += p.x; s.y += p.y; s.z += p.z; s.w += p.w;
  }
  ushort4 o; o.x = f2bf(s.x); o.y = f2bf(s.y); o.z = f2bf(s.z); o.w = f2bf(s.w);
  ((ushort4*)WTpb)[i4] = o;
}

extern "C" void kernel_launch(void* const* d_in, const int* in_sizes, int n_in,
                              void* d_out, int out_size, void* d_ws, size_t ws_size,
                              hipStream_t stream)
{
  const float* t    = (const float*)d_in[0];   // [8,1024,3072]
  const float* W    = (const float*)d_in[1];   // [3072,768]
  const float* bias = (const float*)d_in[2];   // [3072]
  float* out = (float*)d_out;                  // [8192,768] fp32

  char* p = (char*)d_ws;                       // 51,904,512 B used
  u16*   WTb  = (u16*)(p + 0);                 //  4,718,592  bf16 W^T  [768,3072]
  u16*   Wb   = (u16*)(p + 4718592);           //  4,718,592  bf16 W    [3072,768]
  u16*   Eb   = (u16*)(p + 9437184);           //  1,179,648  bf16 E    [768,768]
  u16*   Mb   = (u16*)(p + 10616832);          //  1,179,648  bf16 M    [768,768]
  u16*   WTpb = (u16*)(p + 11796480);          //  4,718,592  bf16 W'^T [768,3072]
  float* Ef   = (float*)(p + 16515072);        //  2,359,296  E fp32
  float* Ep   = (float*)(p + 18874368);        // 18,874,368  E partials [8][768^2]
  float* P2p  = (float*)(p + 37748736);        // 14,155,776  E^2 partials [6][768^2]
  float* Wp   = (float*)(p + 18874368);        // 28,311,552  W'T partials [3][768,3072]
                                               // (aliases Ep+P2p head; E chain done first)
  const float lr = 0.001f;

  // 1. Wb + WTb
  conv_w<<<2304, 256, 0, stream>>>(W, Wb, WTb);
  // 2. E partials = lr * WT @ WT^T : K=3072, z=8, kc=384 (3 outer iters)
  gemm_d<1><<<dim3(6, 4, 8), 256, 0, stream>>>(
      WTb, nullptr, WTb, Ep, lr, 3072, 768, 384, 589824);
  // 3. Ef, Eb
  red_e<<<576, 256, 0, stream>>>(Ep, Ef, Eb);
  // 4. E^2 partials = Eb @ Eb^T (E symmetric): K=768, z=6, kc=128
  gemm_d<1><<<dim3(6, 4, 6), 256, 0, stream>>>(
      Eb, nullptr, Eb, P2p, 1.f, 768, 768, 128, 589824);
  // 5. Mb = bf16(0.01 I + lr(-45E + 120E^2))
  red_m<<<576, 256, 0, stream>>>(P2p, Ef, Mb, lr);
  // 6. W'T partials = Mb @ Wb^T : [768,3072], K=768, z=3, kc=256 (overwrites Ep/P2p)
  gemm_d<1><<<dim3(6, 16, 3), 256, 0, stream>>>(
      Mb, nullptr, Wb, Wp, 1.f, 768, 3072, 256, 2359296);
  // 7. W'Tb = bf16(sum Wp)
  red_w<<<2304, 256, 0, stream>>>(Wp, WTpb);
  // 8. out = (t - b) @ W' : fp32 A direct, K=3072, grid 64x4 = 256 blocks (1/CU)
  gemm_d<0><<<dim3(64, 4, 1), 256, 0, stream>>>(
      t, bias, WTpb, out, 1.f, 3072, 768, 3072, 0);
}

// Round 5
// 276.402 us; speedup vs baseline: 1.7863x; 1.7863x over previous
//
#include <hip/hip_runtime.h>
#include <stdint.h>

// PCLayer closed form: out = (t-b) @ W @ M,  M = 0.01*I + lr*(-45E + 120E^2),
// E = lr*W^T W  (||E||~0.009; E^3 term < 1e-5, verified immaterial in r2/r3).
// All GEMMs use the m97-verified gl2lds+LDS structure (r4's LDS-free variant
// was 2x slower: dependent global loads on the MFMA path, 6% MfmaUtil).
// BK=64 = two 32-wide sub-tiles per barrier (same LDS sub-layout as m97),
// halving barrier-drain stalls. 7 launches, no atomics, no memset.

typedef short bf16x8 __attribute__((ext_vector_type(8)));   // 8 bf16 = 4 VGPRs
typedef float f32x4  __attribute__((ext_vector_type(4)));
typedef unsigned short u16;
typedef unsigned int uint_as1 __attribute__((address_space(1)));
typedef unsigned int uint_as3 __attribute__((address_space(3)));

__device__ __forceinline__ u16 f2bf(float f) {  // round-to-nearest-even
  union { float f; unsigned int i; } x; x.f = f;
  unsigned int r = x.i + 0x7fffu + ((x.i >> 16) & 1u);
  return (u16)(r >> 16);
}
__device__ __forceinline__ void gl2lds16(const void* g, void* l) {
  // async 16B/lane global->LDS; LDS dst = wave-uniform base + lane*16
  __builtin_amdgcn_global_load_lds((uint_as1*)(uintptr_t)g,
                                   (uint_as3*)(uintptr_t)l, 16, 0, 0);
}

// C[M,N] = alpha * A[M,K] @ B[N,K]^T  (bf16 row-major, lda=ldb=K).
// Tile TM x 128, K-chunk 32*NK per barrier (each 32-sub-tile uses the m97
// LDS layout: row*32 + q*8). EPI 0: fp32 store at Cf + blockIdx.z*zstride
// (split-K partials, or plain store with z=1). EPI 1: bf16 store to Cb.
template<int TM, int NK, int EPI>
__global__ __launch_bounds__(256, 2)
void gemm_lds(const u16* __restrict__ A, const u16* __restrict__ B,
              float* __restrict__ Cf, u16* __restrict__ Cb,
              float alpha, int K, int ldc, int kc, long zstride)
{
  constexpr int FM  = TM / 32;   // A frags per wave
  constexpr int RPW = TM / 4;    // A rows staged per wave
  __shared__ u16 As[TM * 32 * NK];
  __shared__ u16 Bs[128 * 32 * NK];
  const int tid = threadIdx.x, w = tid >> 6, lane = tid & 63;
  const int lm = lane & 15, quad = lane >> 4;
  const int wm = w & 1, wn = w >> 1;
  const int m0 = blockIdx.x * TM, n0 = blockIdx.y * 128;
  const long k0 = (long)blockIdx.z * kc;
  const int r = lane >> 2, q = lane & 3;
  const u16* Ag = A + (long)(m0 + w * RPW + r) * K + k0 + q * 8;
  const u16* Bg = B + (long)(n0 + w * 32 + r) * K + k0 + q * 8;
  u16* Asl = As + w * RPW * 32;   // wave-uniform stage bases
  u16* Bsl = Bs + w * 1024;

  f32x4 acc[FM][4] = {};

  for (int kk = 0; kk < kc; kk += 32 * NK) {
#pragma unroll
    for (int h = 0; h < NK; ++h) {
#pragma unroll
      for (int l = 0; l < RPW / 16; ++l)
        gl2lds16(Ag + (long)(l * 16) * K + kk + h * 32,
                 Asl + h * TM * 32 + l * 512);
      gl2lds16(Bg + kk + h * 32, Bsl + h * 4096);
      gl2lds16(Bg + 16 * (long)K + kk + h * 32, Bsl + h * 4096 + 512);
    }
    __syncthreads();
#pragma unroll
    for (int h = 0; h < NK; ++h) {
      bf16x8 af[FM], bv[4];
#pragma unroll
      for (int i = 0; i < FM; ++i)
        af[i] = *(const bf16x8*)(As + h * TM * 32 +
                                 (wm * (TM / 2) + i * 16 + lm) * 32 + quad * 8);
#pragma unroll
      for (int j = 0; j < 4; ++j)
        bv[j] = *(const bf16x8*)(Bs + h * 4096 +
                                 (wn * 64 + j * 16 + lm) * 32 + quad * 8);
#pragma unroll
      for (int i = 0; i < FM; ++i)
#pragma unroll
        for (int j = 0; j < 4; ++j)
          acc[i][j] = __builtin_amdgcn_mfma_f32_16x16x32_bf16(af[i], bv[j],
                                                              acc[i][j], 0, 0, 0);
    }
    __syncthreads();
  }

  // C/D layout (m89-verified): col = lane&15, row = quad*4 + reg
  const int rbase = m0 + wm * (TM / 2) + quad * 4;
  const int cbase = n0 + wn * 64 + lm;
  const long zoff = (long)blockIdx.z * zstride;
#pragma unroll
  for (int i = 0; i < FM; ++i)
#pragma unroll
    for (int j = 0; j < 4; ++j) {
      const int col = cbase + j * 16;
#pragma unroll
      for (int rr = 0; rr < 4; ++rr) {
        const long idx = (long)(rbase + i * 16 + rr) * ldc + col;
        const float v = alpha * acc[i][j][rr];
        if constexpr (EPI == 0) Cf[zoff + idx] = v;
        else                    Cb[idx] = f2bf(v);
      }
    }
}

// Fused converts: tb = bf16(t - b) [8192,3072]; Wb = bf16(W) [3072,768];
// WTb = bf16(W)^T [768,3072].
__global__ void conv_all(const float* __restrict__ t, const float* __restrict__ bias,
                         const float* __restrict__ W, u16* __restrict__ tb,
                         u16* __restrict__ Wb, u16* __restrict__ WTb)
{
  const int bx = blockIdx.x, tid = threadIdx.x;
  if (bx < 24576) {                        // t: 6,291,456 float4
    const long i4 = (long)bx * 256 + tid;
    const float4 v = ((const float4*)t)[i4];
    const float4 bb = ((const float4*)bias)[(int)(i4 % 768)];
    ushort4 o;
    o.x = f2bf(v.x - bb.x); o.y = f2bf(v.y - bb.y);
    o.z = f2bf(v.z - bb.z); o.w = f2bf(v.w - bb.w);
    ((ushort4*)tb)[i4] = o;
  } else {                                 // W: 589,824 float4
    const int i4 = (bx - 24576) * 256 + tid;
    const float4 v = ((const float4*)W)[i4];
    ushort4 o;
    o.x = f2bf(v.x); o.y = f2bf(v.y); o.z = f2bf(v.z); o.w = f2bf(v.w);
    ((ushort4*)Wb)[i4] = o;
    const int rr = i4 / 192, c = (i4 - rr * 192) * 4;
    WTb[(long)(c + 0) * 3072 + rr] = o.x;  // 2B scatter; 4.7MB, L2/L3-absorbed
    WTb[(long)(c + 1) * 3072 + rr] = o.y;
    WTb[(long)(c + 2) * 3072 + rr] = o.z;
    WTb[(long)(c + 3) * 3072 + rr] = o.w;
  }
}

// Ef = sum_{z<4} Ep[z];  Eb = bf16(Ef)   (147456 float4)
__global__ void red_e(const float* __restrict__ Ep, float* __restrict__ Ef,
                      u16* __restrict__ Eb)
{
  const int i4 = blockIdx.x * 256 + threadIdx.x;
  float4 s = make_float4(0.f, 0.f, 0.f, 0.f);
#pragma unroll
  for (int z = 0; z < 4; ++z) {
    const float4 p = ((const float4*)Ep)[(long)z * 147456 + i4];
    s.x += p.x; s.y += p.y; s.z += p.z; s.w += p.w;
  }
  ((float4*)Ef)[i4] = s;
  ushort4 o; o.x = f2bf(s.x); o.y = f2bf(s.y); o.z = f2bf(s.z); o.w = f2bf(s.w);
  ((ushort4*)Eb)[i4] = o;
}

// Mb = bf16(0.01*I + lr*(-45*Ef + 120*sum_{z<4} P2p[z]))
__global__ void red_m(const float* __restrict__ P2p, const float* __restrict__ Ef,
                      u16* __restrict__ Mb, float lr)
{
  const int i4 = blockIdx.x * 256 + threadIdx.x;
  float4 s = make_float4(0.f, 0.f, 0.f, 0.f);
#pragma unroll
  for (int z = 0; z < 4; ++z) {
    const float4 p = ((const float4*)P2p)[(long)z * 147456 + i4];
    s.x += p.x; s.y += p.y; s.z += p.z; s.w += p.w;
  }
  const float4 e = ((const float4*)Ef)[i4];
  const int rr = i4 / 192, c = (i4 - rr * 192) * 4;
  float4 m;
  m.x = lr * (-45.f * e.x + 120.f * s.x) + (rr == c + 0 ? 0.01f : 0.f);
  m.y = lr * (-45.f * e.y + 120.f * s.y) + (rr == c + 1 ? 0.01f : 0.f);
  m.z = lr * (-45.f * e.z + 120.f * s.z) + (rr == c + 2 ? 0.01f : 0.f);
  m.w = lr * (-45.f * e.w + 120.f * s.w) + (rr == c + 3 ? 0.01f : 0.f);
  ushort4 o; o.x = f2bf(m.x); o.y = f2bf(m.y); o.z = f2bf(m.z); o.w = f2bf(m.w);
  ((ushort4*)Mb)[i4] = o;
}

extern "C" void kernel_launch(void* const* d_in, const int* in_sizes, int n_in,
                              void* d_out, int out_size, void* d_ws, size_t ws_size,
                              hipStream_t stream)
{
  const float* t    = (const float*)d_in[0];   // [8,1024,3072]
  const float* W    = (const float*)d_in[1];   // [3072,768]
  const float* bias = (const float*)d_in[2];   // [3072]
  float* out = (float*)d_out;                  // [8192,768] fp32

  char* p = (char*)d_ws;                       // 78,643,200 B used (r1 proved 79.8MB ok)
  u16*   tb  = (u16*)(p + 0);                  // 50,331,648  bf16 t-b  [8192,3072]
  u16*   Wb  = (u16*)(p + 50331648);           //  4,718,592  bf16 W    [3072,768]
  u16*   WTb = (u16*)(p + 55050240);           //  4,718,592  bf16 W^T  [768,3072]
  u16*   Apb = (u16*)(p + 59768832);           //  4,718,592  bf16 A'^T [768,3072]
  u16*   Eb  = (u16*)(p + 64487424);           //  1,179,648  bf16 E    [768,768]
  u16*   Mb  = (u16*)(p + 65667072);           //  1,179,648  bf16 M    [768,768]
  float* Ef  = (float*)(p + 66846720);         //  2,359,296  E fp32
  float* R   = (float*)(p + 69206016);         //  9,437,184  split-K partials [4][768^2]
                                               // (reused: Ep, then P2p — sequential)
  const float lr = 0.001f;

  // 1. converts (t, W) — pure BW, ~155 MB traffic
  conv_all<<<26880, 256, 0, stream>>>(t, bias, W, tb, Wb, WTb);
  // 2. E partials = lr * WT @ WT^T : K=3072, z=4, kc=768 (12 iters @BK64)
  gemm_lds<64, 2, 0><<<dim3(12, 6, 4), 256, 0, stream>>>(
      WTb, WTb, R, nullptr, lr, 3072, 768, 768, 589824);
  // 3. Ef = sum(R); Eb = bf16(Ef)
  red_e<<<576, 256, 0, stream>>>(R, Ef, Eb);
  // 4. E^2 partials = Eb @ Eb^T (E symmetric): K=768, z=4, kc=192 (3 iters)
  gemm_lds<64, 2, 0><<<dim3(12, 6, 4), 256, 0, stream>>>(
      Eb, Eb, R, nullptr, 1.f, 768, 768, 192, 589824);
  // 5. Mb = bf16(0.01 I + lr(-45E + 120E^2))
  red_m<<<576, 256, 0, stream>>>(R, Ef, Mb, lr);
  // 6. A'^T = M @ W^T (M symmetric), bf16 direct: K=768, grid 12x24 (12 iters)
  gemm_lds<64, 2, 1><<<dim3(12, 24, 1), 256, 0, stream>>>(
      Mb, Wb, nullptr, Apb, 1.f, 768, 3072, 768, 0);
  // 7. out = tb @ A' : TM=128, BK=64, grid 64x6=384 blocks, 48 barriers
  gemm_lds<128, 2, 0><<<dim3(64, 6, 1), 256, 0, stream>>>(
      tb, Apb, out, nullptr, 1.f, 3072, 768, 3072, 0);
}

// Round 6
// 270.660 us; speedup vs baseline: 1.8242x; 1.0212x over previous
//
#include <hip/hip_runtime.h>
#include <stdint.h>

// PCLayer closed form (y-route):
//   y  = (t - b) @ W                    [8192,768]   GEMM1, K=3072
//   out = 0.01*y + lr * y @ S''                      GEMM2, K=768
//   S'' = -45E + 120E^2,  E = lr*W^T W  (E^3 term < 1e-5; validated r2/r3)
// All GEMMs: m97 gl2lds+LDS structure, BK=64 (r5-proven). Small GEMMs:
// split-K fp32 partials + reduce (no atomics). W transpose via LDS tile
// (r5's 2B scatter inflated WRITE_SIZE 2x). 7 launches, no memset.

typedef short bf16x8 __attribute__((ext_vector_type(8)));   // 8 bf16 = 4 VGPRs
typedef float f32x4  __attribute__((ext_vector_type(4)));
typedef unsigned short u16;
typedef unsigned int uint_as1 __attribute__((address_space(1)));
typedef unsigned int uint_as3 __attribute__((address_space(3)));

__device__ __forceinline__ float bf2f(u16 u) {
  union { unsigned int i; float f; } x; x.i = ((unsigned int)u) << 16; return x.f;
}
__device__ __forceinline__ u16 f2bf(float f) {  // round-to-nearest-even
  union { float f; unsigned int i; } x; x.f = f;
  unsigned int r = x.i + 0x7fffu + ((x.i >> 16) & 1u);
  return (u16)(r >> 16);
}
__device__ __forceinline__ void gl2lds16(const void* g, void* l) {
  // async 16B/lane global->LDS; LDS dst = wave-uniform base + lane*16
  __builtin_amdgcn_global_load_lds((uint_as1*)(uintptr_t)g,
                                   (uint_as3*)(uintptr_t)l, 16, 0, 0);
}

// C[M,N] = alpha * A[M,K] @ B[N,K]^T  (bf16 row-major, lda=ldb=K).
// Tile TM x 128, K-chunk 32*NK per barrier (m97 LDS sub-layout per 32-slab).
// EPI 0: fp32 store at Cf + blockIdx.z*zstride (split-K partials / plain)
// EPI 1: bf16 store to Cb
// EPI 2: fp32 store Cf = alpha*acc + beta*bf2f(Yb[idx])
template<int TM, int NK, int EPI>
__global__ __launch_bounds__(256, 2)
void gemm_lds(const u16* __restrict__ A, const u16* __restrict__ B,
              float* __restrict__ Cf, u16* __restrict__ Cb,
              const u16* __restrict__ Yb, float alpha, float beta,
              int K, int ldc, int kc, long zstride)
{
  constexpr int FM  = TM / 32;   // A frags per wave
  constexpr int RPW = TM / 4;    // A rows staged per wave
  __shared__ u16 As[TM * 32 * NK];
  __shared__ u16 Bs[128 * 32 * NK];
  const int tid = threadIdx.x, w = tid >> 6, lane = tid & 63;
  const int lm = lane & 15, quad = lane >> 4;
  const int wm = w & 1, wn = w >> 1;
  const int m0 = blockIdx.x * TM, n0 = blockIdx.y * 128;
  const long k0 = (long)blockIdx.z * kc;
  const int r = lane >> 2, q = lane & 3;
  const u16* Ag = A + (long)(m0 + w * RPW + r) * K + k0 + q * 8;
  const u16* Bg = B + (long)(n0 + w * 32 + r) * K + k0 + q * 8;
  u16* Asl = As + w * RPW * 32;   // wave-uniform stage bases
  u16* Bsl = Bs + w * 1024;

  f32x4 acc[FM][4] = {};

  for (int kk = 0; kk < kc; kk += 32 * NK) {
#pragma unroll
    for (int h = 0; h < NK; ++h) {
#pragma unroll
      for (int l = 0; l < RPW / 16; ++l)
        gl2lds16(Ag + (long)(l * 16) * K + kk + h * 32,
                 Asl + h * TM * 32 + l * 512);
      gl2lds16(Bg + kk + h * 32, Bsl + h * 4096);
      gl2lds16(Bg + 16 * (long)K + kk + h * 32, Bsl + h * 4096 + 512);
    }
    __syncthreads();
#pragma unroll
    for (int h = 0; h < NK; ++h) {
      bf16x8 af[FM], bv[4];
#pragma unroll
      for (int i = 0; i < FM; ++i)
        af[i] = *(const bf16x8*)(As + h * TM * 32 +
                                 (wm * (TM / 2) + i * 16 + lm) * 32 + quad * 8);
#pragma unroll
      for (int j = 0; j < 4; ++j)
        bv[j] = *(const bf16x8*)(Bs + h * 4096 +
                                 (wn * 64 + j * 16 + lm) * 32 + quad * 8);
#pragma unroll
      for (int i = 0; i < FM; ++i)
#pragma unroll
        for (int j = 0; j < 4; ++j)
          acc[i][j] = __builtin_amdgcn_mfma_f32_16x16x32_bf16(af[i], bv[j],
                                                              acc[i][j], 0, 0, 0);
    }
    __syncthreads();
  }

  // C/D layout (m89-verified): col = lane&15, row = quad*4 + reg
  const int rbase = m0 + wm * (TM / 2) + quad * 4;
  const int cbase = n0 + wn * 64 + lm;
  const long zoff = (long)blockIdx.z * zstride;
#pragma unroll
  for (int i = 0; i < FM; ++i)
#pragma unroll
    for (int j = 0; j < 4; ++j) {
      const int col = cbase + j * 16;
#pragma unroll
      for (int rr = 0; rr < 4; ++rr) {
        const long idx = (long)(rbase + i * 16 + rr) * ldc + col;
        const float v = alpha * acc[i][j][rr];
        if constexpr (EPI == 0)      Cf[zoff + idx] = v;
        else if constexpr (EPI == 1) Cb[idx] = f2bf(v);
        else                         Cf[idx] = v + beta * bf2f(Yb[idx]);
      }
    }
}

// Fused prep: tb = bf16(t - b) [8192,3072]  (blocks 0..24575)
//             WTb = bf16(W)^T [768,3072] via LDS-tiled transpose, coalesced
//             both sides (blocks 24576..25151; 48 x 12 tiles of 64x64)
__global__ void conv_all(const float* __restrict__ t, const float* __restrict__ bias,
                         const float* __restrict__ W, u16* __restrict__ tb,
                         u16* __restrict__ WTb)
{
  __shared__ u16 lds[64 * 72];              // [i_local][o_local], stride 72
  const int bx = blockIdx.x, tid = threadIdx.x;
  if (bx < 24576) {                         // t: 6,291,456 float4
    const long i4 = (long)bx * 256 + tid;
    const float4 v = ((const float4*)t)[i4];
    const float4 bb = ((const float4*)bias)[(int)(i4 % 768)];
    ushort4 o;
    o.x = f2bf(v.x - bb.x); o.y = f2bf(v.y - bb.y);
    o.z = f2bf(v.z - bb.z); o.w = f2bf(v.w - bb.w);
    ((ushort4*)tb)[i4] = o;
  } else {
    const int bt = bx - 24576;              // tile (to, ti): o0 = to*64, i0 = ti*64
    const int o0 = (bt / 12) * 64, i0 = (bt % 12) * 64;
    const int ol = tid >> 2, cg = tid & 3;  // 64 o-rows, 4 col-groups
#pragma unroll
    for (int p = 0; p < 4; ++p) {           // 16 float4 per o-row
      const float4 v = *(const float4*)(W + (long)(o0 + ol) * 768 + i0 + (cg + p * 4) * 4);
      const int ib = (cg + p * 4) * 4;
      lds[(ib + 0) * 72 + ol] = f2bf(v.x);
      lds[(ib + 1) * 72 + ol] = f2bf(v.y);
      lds[(ib + 2) * 72 + ol] = f2bf(v.z);
      lds[(ib + 3) * 72 + ol] = f2bf(v.w);
    }
    __syncthreads();
    const int cl = tid >> 2, og = tid & 3;  // 64 i-rows, 4 o-groups of 16
    const u16* src = lds + cl * 72 + og * 16;
    u16* dst = WTb + (long)(i0 + cl) * 3072 + o0 + og * 16;
    ((ushort4*)dst)[0] = ((const ushort4*)src)[0];
    ((ushort4*)dst)[1] = ((const ushort4*)src)[1];
    ((ushort4*)dst)[2] = ((const ushort4*)src)[2];
    ((ushort4*)dst)[3] = ((const ushort4*)src)[3];
  }
}

// Ef = sum_{z<6} R[z];  Eb = bf16(Ef)   (147456 float4)
__global__ void red_e(const float* __restrict__ R, float* __restrict__ Ef,
                      u16* __restrict__ Eb)
{
  const int i4 = blockIdx.x * 256 + threadIdx.x;
  float4 s = make_float4(0.f, 0.f, 0.f, 0.f);
#pragma unroll
  for (int z = 0; z < 6; ++z) {
    const float4 p = ((const float4*)R)[(long)z * 147456 + i4];
    s.x += p.x; s.y += p.y; s.z += p.z; s.w += p.w;
  }
  ((float4*)Ef)[i4] = s;
  ushort4 o; o.x = f2bf(s.x); o.y = f2bf(s.y); o.z = f2bf(s.z); o.w = f2bf(s.w);
  ((ushort4*)Eb)[i4] = o;
}

// Spb = bf16(-45*Ef + 120*sum_{z<6} R[z])
__global__ void red_s(const float* __restrict__ R, const float* __restrict__ Ef,
                      u16* __restrict__ Spb)
{
  const int i4 = blockIdx.x * 256 + threadIdx.x;
  float4 s = make_float4(0.f, 0.f, 0.f, 0.f);
#pragma unroll
  for (int z = 0; z < 6; ++z) {
    const float4 p = ((const float4*)R)[(long)z * 147456 + i4];
    s.x += p.x; s.y += p.y; s.z += p.z; s.w += p.w;
  }
  const float4 e = ((const float4*)Ef)[i4];
  ushort4 o;
  o.x = f2bf(-45.f * e.x + 120.f * s.x);
  o.y = f2bf(-45.f * e.y + 120.f * s.y);
  o.z = f2bf(-45.f * e.z + 120.f * s.z);
  o.w = f2bf(-45.f * e.w + 120.f * s.w);
  ((ushort4*)Spb)[i4] = o;
}

extern "C" void kernel_launch(void* const* d_in, const int* in_sizes, int n_in,
                              void* d_out, int out_size, void* d_ws, size_t ws_size,
                              hipStream_t stream)
{
  const float* t    = (const float*)d_in[0];   // [8,1024,3072]
  const float* W    = (const float*)d_in[1];   // [3072,768]
  const float* bias = (const float*)d_in[2];   // [3072]
  float* out = (float*)d_out;                  // [8192,768] fp32

  char* p = (char*)d_ws;                       // 73,924,608 B used (< r1's proven 79.8MB)
  u16*   tb  = (u16*)(p + 0);                  // 50,331,648  bf16 t-b  [8192,3072]
  u16*   WTb = (u16*)(p + 50331648);           //  4,718,592  bf16 W^T  [768,3072]
  float* Ef  = (float*)(p + 55050240);         //  2,359,296  E fp32    [768,768]
  u16*   Eb  = (u16*)(p + 57409536);           //  1,179,648  bf16 E
  u16*   Spb = (u16*)(p + 58589184);           //  1,179,648  bf16 S''
  float* R   = (float*)(p + 59768832);         // 14,155,776  partials [6][768^2]
  u16*   yb  = (u16*)(p + 59768832);           // 12,582,912  bf16 y [8192,768]
                                               // (yb aliases R: R live steps 2-5,
                                               //  yb live steps 6-7 — disjoint)
  const float lr = 0.001f;

  // 1. tb + WTb (LDS-tiled transpose; no partial-line scatter)
  conv_all<<<25152, 256, 0, stream>>>(t, bias, W, tb, WTb);
  // 2. E partials = lr * WT @ WT^T : K=3072, z=6, kc=512 (8 iters @BK64),
  //    grid 432 blocks (~1.7/CU) to overlap serial-iter latency
  gemm_lds<64, 2, 0><<<dim3(12, 6, 6), 256, 0, stream>>>(
      WTb, WTb, R, nullptr, nullptr, lr, 0.f, 3072, 768, 512, 589824);
  // 3. Ef = sum(R); Eb = bf16(Ef)
  red_e<<<576, 256, 0, stream>>>(R, Ef, Eb);
  // 4. E^2 partials = Eb @ Eb^T (E symmetric): K=768, z=6, kc=128 (2 iters)
  gemm_lds<64, 2, 0><<<dim3(12, 6, 6), 256, 0, stream>>>(
      Eb, Eb, R, nullptr, nullptr, 1.f, 0.f, 768, 768, 128, 589824);
  // 5. Spb = bf16(-45E + 120E^2)
  red_s<<<576, 256, 0, stream>>>(R, Ef, Spb);
  // 6. GEMM1: yb = bf16(tb @ W) : TM=128, BK=64, grid 64x6=384, 48 barriers
  gemm_lds<128, 2, 1><<<dim3(64, 6, 1), 256, 0, stream>>>(
      tb, WTb, nullptr, yb, nullptr, 1.f, 0.f, 3072, 768, 3072, 0);
  // 7. GEMM2: out = lr*(yb @ S''^T) + 0.01*yb : K=768, 6 iters, grid 64x6
  gemm_lds<128, 2, 2><<<dim3(64, 6, 1), 256, 0, stream>>>(
      yb, Spb, out, nullptr, yb, lr, 0.01f, 768, 768, 768, 0);
}